// Round 4
// baseline (816.859 us; speedup 1.0000x reference)
//
#include <hip/hip_runtime.h>

#define KSTATES 64

__device__ __forceinline__ float wave_max64(float v) {
#pragma unroll
  for (int off = 32; off; off >>= 1) v = fmaxf(v, __shfl_xor(v, off, 64));
  return v;
}

__device__ __forceinline__ float wave_sum64(float v) {
#pragma unroll
  for (int off = 32; off; off >>= 1) v += __shfl_xor(v, off, 64);
  return v;
}

__device__ __forceinline__ float bcast0(float v) {
  return __int_as_float(__builtin_amdgcn_readfirstlane(__float_as_int(v)));
}

// wave_ror:1 DPP rotate across all 64 lanes — pure VALU, no LDS pipe.
__device__ __forceinline__ float ror1f(float v) {
  return __int_as_float(
      __builtin_amdgcn_mov_dpp(__float_as_int(v), 0x13C, 0xF, 0xF, false));
}
__device__ __forceinline__ int ror1i(int v) {
  return __builtin_amdgcn_mov_dpp(v, 0x13C, 0xF, 0xF, false);
}

__global__ __launch_bounds__(64) void crf_kernel(
    const float* __restrict__ emissions,   // [B, T, K]
    const float* __restrict__ transitions, // [K, K]
    const float* __restrict__ start_trans, // [K]
    const float* __restrict__ end_trans,   // [K]
    const int* __restrict__ labels,        // [B, T]
    const int* __restrict__ sent_len,      // [B]
    float* __restrict__ out,               // scalar
    int T, float inv_B) {
  const int b = blockIdx.x;
  const int j = threadIdx.x;  // state index == lane
  const int sl = sent_len[b];
  const int tmax = T - 1;

  const float* em = emissions + (size_t)b * T * KSTATES;
  const int* lbl = labels + (size_t)b * T;

  // ---- gold score: lane-parallel over time (independent, pipelined) ----
  float g = 0.f;
#pragma unroll 4
  for (int t0 = j; t0 < T; t0 += KSTATES) {
    if (t0 < sl) {
      int lab = lbl[t0];
      float v = em[(size_t)t0 * KSTATES + lab];
      if (t0 == 0)
        v += start_trans[lab];
      else
        v += transitions[lbl[t0 - 1] * KSTATES + lab];
      if (t0 == sl - 1) v += end_trans[lab];
      g += v;
    }
  }
  float gold = wave_sum64(g);

  // ---- preload rotated exp(transitions): cp[k][j] = exp(T[P^k(j)][j]),
  // where P is whatever permutation wave_ror:1 implements (direction-proof:
  // we apply the *same* primitive to the lane index). ----
  int idx = j;
  float cp[KSTATES];
#pragma unroll
  for (int k = 0; k < KSTATES; ++k) {
    cp[k] = __expf(transitions[idx * KSTATES + j]);
    idx = ror1i(idx);
  }

  // ---- forward scan: exp-space linear recurrence, systolic DPP matvec ----
  const float* emj = em + j;
  float e0 = emj[0];
  float alpha0 = start_trans[j] + e0;
  float m0 = wave_max64(alpha0);
  float a = __expf(alpha0 - m0);  // linear-space, normalized
  float C = m0;                   // log offset
  float r = 1.0f;                 // pending renormalizer (applied exactly once)

  float ring[8];
#pragma unroll
  for (int q = 0; q < 8; ++q) ring[q] = emj[(size_t)min(1 + q, tmax) * KSTATES];

  for (int t = 1; t < sl; t += 8) {
#pragma unroll
    for (int q = 0; q < 8; ++q) {
      if (t + q < sl) {  // sl is wave-uniform -> scalar branch, no divergence
        float emit = ring[q];
        ring[q] = emj[(size_t)min(t + q + 8, tmax) * KSTATES];

        float E = __expf(emit);
        if (q == 0 || q == 4) {  // apply pending renorm exactly once
          E *= r;
          r = 1.0f;
        }

        // S_j = sum_i a_i * expT[i][j] via 64-stage lane rotation (no LDS)
        float rot = a;
        float acc0 = 0.f, acc1 = 0.f, acc2 = 0.f, acc3 = 0.f;
#pragma unroll
        for (int k = 0; k < KSTATES; k += 4) {
          acc0 = fmaf(rot, cp[k + 0], acc0); rot = ror1f(rot);
          acc1 = fmaf(rot, cp[k + 1], acc1); rot = ror1f(rot);
          acc2 = fmaf(rot, cp[k + 2], acc2); rot = ror1f(rot);
          acc3 = fmaf(rot, cp[k + 3], acc3); rot = ror1f(rot);
        }
        float s = (acc0 + acc1) + (acc2 + acc3);
        a = s * E;

        if (q == 3 || q == 7) {  // renorm every 4 steps (off critical path)
          float ar = bcast0(a);
          C += __logf(ar);
          r = __builtin_amdgcn_rcpf(ar);
        }
      }
    }
  }

  // fwd = logsumexp(alpha + end); pending r folded in here
  float v = a * __expf(end_trans[j]);
  float sum = wave_sum64(v);
  float fwd = C + __logf(sum * r);

  if (j == 0) atomicAdd(out, (fwd - gold) * inv_B);
}

extern "C" void kernel_launch(void* const* d_in, const int* in_sizes, int n_in,
                              void* d_out, int out_size, void* d_ws, size_t ws_size,
                              hipStream_t stream) {
  const float* emissions = (const float*)d_in[0];
  const float* transitions = (const float*)d_in[1];
  const float* start_trans = (const float*)d_in[2];
  const float* end_trans = (const float*)d_in[3];
  const int* labels = (const int*)d_in[4];
  const int* sent_len = (const int*)d_in[5];
  float* out = (float*)d_out;

  const int B = in_sizes[5];
  const int T = in_sizes[4] / B;

  hipMemsetAsync(out, 0, sizeof(float), stream);
  crf_kernel<<<B, KSTATES, 0, stream>>>(
      emissions, transitions, start_trans, end_trans, labels, sent_len, out, T,
      1.0f / (float)B);
}

// Round 5
// 550.872 us; speedup vs baseline: 1.4828x; 1.4828x over previous
//
#include <hip/hip_runtime.h>

#define KSTATES 64

__device__ __forceinline__ float wave_max64(float v) {
#pragma unroll
  for (int off = 32; off; off >>= 1) v = fmaxf(v, __shfl_xor(v, off, 64));
  return v;
}

__device__ __forceinline__ float wave_sum64(float v) {
#pragma unroll
  for (int off = 32; off; off >>= 1) v += __shfl_xor(v, off, 64);
  return v;
}

__device__ __forceinline__ float bcast0(float v) {
  return __int_as_float(__builtin_amdgcn_readfirstlane(__float_as_int(v)));
}

// broadcast lane k of v to all lanes via v_readlane (independent, no chain)
__device__ __forceinline__ float rlane(float v, int k) {
  return __int_as_float(__builtin_amdgcn_readlane(__float_as_int(v), k));
}

__global__ __launch_bounds__(64) void crf_kernel(
    const float* __restrict__ emissions,   // [B, T, K]
    const float* __restrict__ transitions, // [K, K]
    const float* __restrict__ start_trans, // [K]
    const float* __restrict__ end_trans,   // [K]
    const int* __restrict__ labels,        // [B, T]
    const int* __restrict__ sent_len,      // [B]
    float* __restrict__ out,               // scalar
    int T, float inv_B) {
  const int b = blockIdx.x;
  const int j = threadIdx.x;  // state index == lane
  const int sl = sent_len[b];
  const int tmax = T - 1;

  const float* em = emissions + (size_t)b * T * KSTATES;
  const int* lbl = labels + (size_t)b * T;

  // ---- gold score: lane-parallel over time (independent, pipelined) ----
  float g = 0.f;
#pragma unroll 4
  for (int t0 = j; t0 < T; t0 += KSTATES) {
    if (t0 < sl) {
      int lab = lbl[t0];
      float v = em[(size_t)t0 * KSTATES + lab];
      if (t0 == 0)
        v += start_trans[lab];
      else
        v += transitions[lbl[t0 - 1] * KSTATES + lab];
      if (t0 == sl - 1) v += end_trans[lab];
      g += v;
    }
  }
  float gold = wave_sum64(g);

  // ---- c[i] = exp(T[i][j]) : column j of exp(transitions), natural order
  float c[KSTATES];
#pragma unroll
  for (int i = 0; i < KSTATES; ++i) c[i] = __expf(transitions[i * KSTATES + j]);

  // ---- forward scan: exp-space linear recurrence, readlane-broadcast matvec
  const float* emj = em + j;
  float e0 = emj[0];
  float alpha0 = start_trans[j] + e0;
  float m0 = wave_max64(alpha0);
  float a = __expf(alpha0 - m0);  // linear-space, normalized
  float C = m0;                   // log offset
  float r = 1.0f;                 // pending renormalizer (applied exactly once)

  float ring[8];
#pragma unroll
  for (int q = 0; q < 8; ++q) ring[q] = emj[(size_t)min(1 + q, tmax) * KSTATES];

  for (int t = 1; t < sl; t += 8) {
#pragma unroll
    for (int q = 0; q < 8; ++q) {
      if (t + q < sl) {  // sl is wave-uniform -> scalar branch, no divergence
        float emit = ring[q];
        ring[q] = emj[(size_t)min(t + q + 8, tmax) * KSTATES];

        float E = __expf(emit);
        if (q == 0 || q == 4) {  // apply pending renorm exactly once
          E *= r;
          r = 1.0f;
        }

        // S_j = sum_i a_i * expT[i][j]; a_i broadcast via independent
        // v_readlane -> SGPR, consumed directly as FMA scalar operand.
        float acc0 = 0.f, acc1 = 0.f, acc2 = 0.f, acc3 = 0.f;
#pragma unroll
        for (int i = 0; i < KSTATES; i += 4) {
          acc0 = fmaf(rlane(a, i + 0), c[i + 0], acc0);
          acc1 = fmaf(rlane(a, i + 1), c[i + 1], acc1);
          acc2 = fmaf(rlane(a, i + 2), c[i + 2], acc2);
          acc3 = fmaf(rlane(a, i + 3), c[i + 3], acc3);
        }
        float s = (acc0 + acc1) + (acc2 + acc3);
        a = s * E;

        if (q == 3 || q == 7) {  // renorm every 4 steps (off critical path)
          float ar = bcast0(a);
          C += __logf(ar);
          r = __builtin_amdgcn_rcpf(ar);
        }
      }
    }
  }

  // fwd = logsumexp(alpha + end); pending r folded in here
  float v = a * __expf(end_trans[j]);
  float sum = wave_sum64(v);
  float fwd = C + __logf(sum * r);

  if (j == 0) atomicAdd(out, (fwd - gold) * inv_B);
}

extern "C" void kernel_launch(void* const* d_in, const int* in_sizes, int n_in,
                              void* d_out, int out_size, void* d_ws, size_t ws_size,
                              hipStream_t stream) {
  const float* emissions = (const float*)d_in[0];
  const float* transitions = (const float*)d_in[1];
  const float* start_trans = (const float*)d_in[2];
  const float* end_trans = (const float*)d_in[3];
  const int* labels = (const int*)d_in[4];
  const int* sent_len = (const int*)d_in[5];
  float* out = (float*)d_out;

  const int B = in_sizes[5];
  const int T = in_sizes[4] / B;

  hipMemsetAsync(out, 0, sizeof(float), stream);
  crf_kernel<<<B, KSTATES, 0, stream>>>(
      emissions, transitions, start_trans, end_trans, labels, sent_len, out, T,
      1.0f / (float)B);
}

// Round 6
// 549.157 us; speedup vs baseline: 1.4875x; 1.0031x over previous
//
#include <hip/hip_runtime.h>

#define KSTATES 64

__device__ __forceinline__ float wave_max64(float v) {
#pragma unroll
  for (int off = 32; off; off >>= 1) v = fmaxf(v, __shfl_xor(v, off, 64));
  return v;
}

__device__ __forceinline__ float wave_sum64(float v) {
#pragma unroll
  for (int off = 32; off; off >>= 1) v += __shfl_xor(v, off, 64);
  return v;
}

__device__ __forceinline__ float bcast0(float v) {
  return __int_as_float(__builtin_amdgcn_readfirstlane(__float_as_int(v)));
}

// broadcast lane k of v to all lanes via v_readlane (independent, no chain)
__device__ __forceinline__ float rlane(float v, int k) {
  return __int_as_float(__builtin_amdgcn_readlane(__float_as_int(v), k));
}

// min-waves/EU = 1: we only ever have 2 waves/CU (512 blocks of 1 wave on
// 256 CUs), so let the register allocator use the full VGPR file and keep
// the exp(transitions) column (64 floats) + emission ring register-resident.
__global__ __launch_bounds__(64, 1) void crf_kernel(
    const float* __restrict__ emissions,   // [B, T, K]
    const float* __restrict__ transitions, // [K, K]
    const float* __restrict__ start_trans, // [K]
    const float* __restrict__ end_trans,   // [K]
    const int* __restrict__ labels,        // [B, T]
    const int* __restrict__ sent_len,      // [B]
    float* __restrict__ out,               // scalar
    int T, float inv_B) {
  const int b = blockIdx.x;
  const int j = threadIdx.x;  // state index == lane
  const int sl = sent_len[b];
  const int tmax = T - 1;

  const float* em = emissions + (size_t)b * T * KSTATES;
  const int* lbl = labels + (size_t)b * T;

  // ---- gold score: lane-parallel over time (independent, pipelined) ----
  float g = 0.f;
#pragma unroll 4
  for (int t0 = j; t0 < T; t0 += KSTATES) {
    if (t0 < sl) {
      int lab = lbl[t0];
      float v = em[(size_t)t0 * KSTATES + lab];
      if (t0 == 0)
        v += start_trans[lab];
      else
        v += transitions[lbl[t0 - 1] * KSTATES + lab];
      if (t0 == sl - 1) v += end_trans[lab];
      g += v;
    }
  }
  float gold = wave_sum64(g);

  // ---- c[i] = exp(T[i][j]) : column j of exp(transitions), natural order
  float c[KSTATES];
#pragma unroll
  for (int i = 0; i < KSTATES; ++i) c[i] = __expf(transitions[i * KSTATES + j]);

  // ---- forward scan: exp-space linear recurrence, readlane-broadcast matvec
  const float* emj = em + j;
  float e0 = emj[0];
  float alpha0 = start_trans[j] + e0;
  float m0 = wave_max64(alpha0);
  float a = __expf(alpha0 - m0);  // linear-space, normalized
  float C = m0;                   // log offset
  float r = 1.0f;                 // pending renormalizer (applied exactly once)

  float ring[8];
#pragma unroll
  for (int q = 0; q < 8; ++q) ring[q] = emj[(size_t)min(1 + q, tmax) * KSTATES];

  for (int t = 1; t < sl; t += 8) {
#pragma unroll
    for (int q = 0; q < 8; ++q) {
      if (t + q < sl) {  // sl is wave-uniform -> scalar branch, no divergence
        float emit = ring[q];
        ring[q] = emj[(size_t)min(t + q + 8, tmax) * KSTATES];

        float E = __expf(emit);
        if (q == 0 || q == 4) {  // apply pending renorm exactly once
          E *= r;
          r = 1.0f;
        }

        // S_j = sum_i a_i * expT[i][j]; a_i broadcast via independent
        // v_readlane -> SGPR, consumed directly as FMA scalar operand.
        float acc0 = 0.f, acc1 = 0.f, acc2 = 0.f, acc3 = 0.f;
#pragma unroll
        for (int i = 0; i < KSTATES; i += 4) {
          acc0 = fmaf(rlane(a, i + 0), c[i + 0], acc0);
          acc1 = fmaf(rlane(a, i + 1), c[i + 1], acc1);
          acc2 = fmaf(rlane(a, i + 2), c[i + 2], acc2);
          acc3 = fmaf(rlane(a, i + 3), c[i + 3], acc3);
        }
        float s = (acc0 + acc1) + (acc2 + acc3);
        a = s * E;

        if (q == 3 || q == 7) {  // renorm every 4 steps (off critical path)
          float ar = bcast0(a);
          C += __logf(ar);
          r = __builtin_amdgcn_rcpf(ar);
        }
      }
    }
  }

  // fwd = logsumexp(alpha + end); pending r folded in here
  float v = a * __expf(end_trans[j]);
  float sum = wave_sum64(v);
  float fwd = C + __logf(sum * r);

  if (j == 0) atomicAdd(out, (fwd - gold) * inv_B);
}

extern "C" void kernel_launch(void* const* d_in, const int* in_sizes, int n_in,
                              void* d_out, int out_size, void* d_ws, size_t ws_size,
                              hipStream_t stream) {
  const float* emissions = (const float*)d_in[0];
  const float* transitions = (const float*)d_in[1];
  const float* start_trans = (const float*)d_in[2];
  const float* end_trans = (const float*)d_in[3];
  const int* labels = (const int*)d_in[4];
  const int* sent_len = (const int*)d_in[5];
  float* out = (float*)d_out;

  const int B = in_sizes[5];
  const int T = in_sizes[4] / B;

  hipMemsetAsync(out, 0, sizeof(float), stream);
  crf_kernel<<<B, KSTATES, 0, stream>>>(
      emissions, transitions, start_trans, end_trans, labels, sent_len, out, T,
      1.0f / (float)B);
}